// Round 2
// baseline (305.681 us; speedup 1.0000x reference)
//
#include <hip/hip_runtime.h>
#include <hip/hip_fp16.h>
#include <cstdint>

#define SEQ 4096
#define DIM 1024

typedef _Float16 f16x8 __attribute__((ext_vector_type(8)));
typedef float f32x4 __attribute__((ext_vector_type(4)));
typedef __attribute__((address_space(1))) void as1_void;
typedef __attribute__((address_space(3))) void as3_void;

// RNE f32 -> fp16 bits (v_cvt_f16_f32)
__device__ __forceinline__ ushort f2h(float f) {
  _Float16 h = (_Float16)f;
  return __builtin_bit_cast(ushort, h);
}

// ---------------- conversions ----------------
__global__ void convert_x_kernel(const float* __restrict__ X, ushort* __restrict__ Xh, int n4) {
  int i = blockIdx.x * blockDim.x + threadIdx.x;
  if (i >= n4) return;
  float4 v = reinterpret_cast<const float4*>(X)[i];
  ushort4 o = { f2h(v.x), f2h(v.y), f2h(v.z), f2h(v.w) };
  reinterpret_cast<ushort4*>(Xh)[i] = o;
}

// Transpose + convert the three weights: Wt[z][n][k] = W_z[k][n], fp16
__global__ void convert_w_kernel(const float* __restrict__ Wk, const float* __restrict__ Wv,
                                 const float* __restrict__ Wq, ushort* __restrict__ Wt) {
  __shared__ float tile[32][33];
  int z = blockIdx.z;
  const float* W = (z == 0) ? Wk : (z == 1) ? Wv : Wq;
  int n0 = blockIdx.x * 32, k0 = blockIdx.y * 32;
  int tx = threadIdx.x, ty = threadIdx.y; // (32,8)
#pragma unroll
  for (int r = 0; r < 4; r++) {
    int k = ty + r * 8;
    tile[k][tx] = W[(size_t)(k0 + k) * DIM + n0 + tx];
  }
  __syncthreads();
  ushort* out = Wt + (size_t)z * DIM * DIM;
#pragma unroll
  for (int r = 0; r < 4; r++) {
    int n = ty + r * 8;
    out[(size_t)(n0 + n) * DIM + k0 + tx] = f2h(tile[tx][n]);
  }
}

// ---------------- GEMM: C[M,N] = A[M,K] * Bt[N,K]^T ----------------
// m97-style: 128x128 tile, BK=64, 4 waves (2x2 of 64x64), 16x16x32 f16 MFMA,
// global_load_lds width=16 staging (contiguous LDS, wave-uniform base).
template <bool F16_OUT>
__global__ __launch_bounds__(256) void gemm_bt(const ushort* __restrict__ A,
                                               const ushort* __restrict__ B,
                                               void* __restrict__ C,
                                               int M, int N, int K) {
  constexpr int BM = 128, BN = 128, BK = 64;
  __shared__ __align__(16) ushort As[BM * BK];
  __shared__ __align__(16) ushort Bs[BN * BK];
  const int tid = threadIdx.x;
  const int wave = tid >> 6, lane = tid & 63;
  const int lane15 = lane & 15, quad = lane >> 4;
  const int wm = (wave & 1) * 64, wn = (wave >> 1) * 64;
  const int m0 = blockIdx.y * BM, n0 = blockIdx.x * BN;

  // staging geometry: per global_load_lds, a wave fills 1KB contiguous LDS;
  // lane's 16B chunk = row (tid>>3) + q*32, elems (tid&7)*8 .. +8
  const int srow = tid >> 3;
  const int skk = (tid & 7) * 8;

  f32x4 acc[4][4];
#pragma unroll
  for (int i = 0; i < 4; i++)
#pragma unroll
    for (int j = 0; j < 4; j++) {
      f32x4 z = {0.f, 0.f, 0.f, 0.f};
      acc[i][j] = z;
    }

  for (int kt = 0; kt < K; kt += BK) {
    __syncthreads();  // previous compute done before overwrite
#pragma unroll
    for (int q = 0; q < 4; q++) {
      const ushort* ga = A + (size_t)(m0 + srow + q * 32) * K + kt + skk;
      __builtin_amdgcn_global_load_lds((const as1_void*)ga,
                                       (as3_void*)&As[wave * 512 + q * 2048], 16, 0, 0);
    }
#pragma unroll
    for (int q = 0; q < 4; q++) {
      const ushort* gb = B + (size_t)(n0 + srow + q * 32) * K + kt + skk;
      __builtin_amdgcn_global_load_lds((const as1_void*)gb,
                                       (as3_void*)&Bs[wave * 512 + q * 2048], 16, 0, 0);
    }
    __syncthreads();  // vmcnt(0) drain + barrier: staging visible
#pragma unroll
    for (int ks = 0; ks < 2; ks++) {
      f16x8 af[4], bfr[4];
#pragma unroll
      for (int i = 0; i < 4; i++)
        af[i] = *reinterpret_cast<const f16x8*>(
            &As[(wm + i * 16 + lane15) * BK + ks * 32 + quad * 8]);
#pragma unroll
      for (int j = 0; j < 4; j++)
        bfr[j] = *reinterpret_cast<const f16x8*>(
            &Bs[(wn + j * 16 + lane15) * BK + ks * 32 + quad * 8]);
#pragma unroll
      for (int i = 0; i < 4; i++)
#pragma unroll
        for (int j = 0; j < 4; j++)
          acc[i][j] = __builtin_amdgcn_mfma_f32_16x16x32_f16(af[i], bfr[j], acc[i][j], 0, 0, 0);
    }
  }

  // epilogue: C/D layout col=lane&15, row=quad*4+reg  [m89-verified, dtype-independent]
  const int rbase = m0 + wm + quad * 4;
  const int cbase = n0 + wn + lane15;
#pragma unroll
  for (int i = 0; i < 4; i++)
#pragma unroll
    for (int j = 0; j < 4; j++)
#pragma unroll
      for (int r = 0; r < 4; r++) {
        int row = rbase + i * 16 + r;
        int col = cbase + j * 16;
        if (F16_OUT)
          reinterpret_cast<ushort*>(C)[(size_t)row * N + col] = f2h(acc[i][j][r]);
        else
          reinterpret_cast<float*>(C)[(size_t)row * N + col] = acc[i][j][r];
      }
}

// ---------------- row softmax: S (f32, SEQ cols) -> P (fp16) ----------------
__global__ __launch_bounds__(256) void softmax_kernel(const float* __restrict__ S,
                                                      ushort* __restrict__ P) {
  const int row = blockIdx.x;
  const float* s = S + (size_t)row * SEQ;
  const int tid = threadIdx.x;
  const int wave = tid >> 6, lane = tid & 63;
  __shared__ float red[4];
  float v[16];
#pragma unroll
  for (int i = 0; i < 4; i++) {
    float4 f = reinterpret_cast<const float4*>(s)[tid + i * 256];
    v[i * 4 + 0] = f.x; v[i * 4 + 1] = f.y; v[i * 4 + 2] = f.z; v[i * 4 + 3] = f.w;
  }
  float m = v[0];
#pragma unroll
  for (int j = 1; j < 16; j++) m = fmaxf(m, v[j]);
#pragma unroll
  for (int o = 32; o > 0; o >>= 1) m = fmaxf(m, __shfl_xor(m, o, 64));
  if (lane == 0) red[wave] = m;
  __syncthreads();
  m = fmaxf(fmaxf(red[0], red[1]), fmaxf(red[2], red[3]));
  __syncthreads();
  float sum = 0.f;
#pragma unroll
  for (int j = 0; j < 16; j++) {
    v[j] = __expf(v[j] - m);
    sum += v[j];
  }
#pragma unroll
  for (int o = 32; o > 0; o >>= 1) sum += __shfl_xor(sum, o, 64);
  if (lane == 0) red[wave] = sum;
  __syncthreads();
  sum = red[0] + red[1] + red[2] + red[3];
  float inv = 1.0f / sum;
  ushort* p = P + (size_t)row * SEQ;
#pragma unroll
  for (int i = 0; i < 4; i++) {
    ushort4 o4 = { f2h(v[i * 4 + 0] * inv), f2h(v[i * 4 + 1] * inv),
                   f2h(v[i * 4 + 2] * inv), f2h(v[i * 4 + 3] * inv) };
    reinterpret_cast<ushort4*>(p)[tid + i * 256] = o4;
  }
}

extern "C" void kernel_launch(void* const* d_in, const int* in_sizes, int n_in,
                              void* d_out, int out_size, void* d_ws, size_t ws_size,
                              hipStream_t stream) {
  const float* X = (const float*)d_in[0];
  const float* Wk = (const float*)d_in[1];
  const float* Wv = (const float*)d_in[2];
  const float* Wq = (const float*)d_in[3];

  char* ws = (char*)d_ws;
  size_t off = 0;
  ushort* Xh = (ushort*)(ws + off); off += (size_t)SEQ * DIM * 2;      // 8 MB
  ushort* Wt = (ushort*)(ws + off); off += (size_t)3 * DIM * DIM * 2;  // 6 MB
  ushort* Kh = (ushort*)(ws + off); off += (size_t)SEQ * DIM * 2;      // 8 MB
  ushort* Qh = (ushort*)(ws + off); off += (size_t)SEQ * DIM * 2;      // 8 MB
  ushort* Vt = (ushort*)(ws + off); off += (size_t)SEQ * DIM * 2;      // 8 MB (V^T: DIM x SEQ)
  float* S = (float*)(ws + off);    off += (size_t)SEQ * SEQ * 4;      // 64 MB
  ushort* P = (ushort*)(ws + off);  off += (size_t)SEQ * SEQ * 2;      // 32 MB  => 134 MB total

  ushort* WtK = Wt;
  ushort* WtV = Wt + (size_t)DIM * DIM;
  ushort* WtQ = Wt + 2 * (size_t)DIM * DIM;

  convert_x_kernel<<<SEQ * DIM / 4 / 256, 256, 0, stream>>>(X, Xh, SEQ * DIM / 4);
  convert_w_kernel<<<dim3(DIM / 32, DIM / 32, 3), dim3(32, 8), 0, stream>>>(Wk, Wv, Wq, Wt);

  // K = Xh @ WkT^T, Q = Xh @ WqT^T  (fp16 out, row-major S x D)
  gemm_bt<true><<<dim3(DIM / 128, SEQ / 128), 256, 0, stream>>>(Xh, WtK, Kh, SEQ, DIM, DIM);
  gemm_bt<true><<<dim3(DIM / 128, SEQ / 128), 256, 0, stream>>>(Xh, WtQ, Qh, SEQ, DIM, DIM);
  // V^T[d,s] = sum_k WvT[d,k] * X[s,k]  -> A=WvT (DIMxDIM), Bt=Xh (SEQxDIM), M=DIM,N=SEQ
  gemm_bt<true><<<dim3(SEQ / 128, DIM / 128), 256, 0, stream>>>(WtV, Xh, Vt, DIM, SEQ, DIM);
  // S = K @ Q^T (fp32 out)
  gemm_bt<false><<<dim3(SEQ / 128, SEQ / 128), 256, 0, stream>>>(Kh, Qh, S, SEQ, SEQ, DIM);
  // row softmax -> P fp16
  softmax_kernel<<<SEQ, 256, 0, stream>>>(S, P);
  // O = P @ V = P (SEQxSEQ) * Vt^T ; A=P, Bt=Vt (DIM x SEQ), fp32 out to d_out
  gemm_bt<false><<<dim3(DIM / 128, SEQ / 128), 256, 0, stream>>>(P, Vt, d_out, SEQ, DIM, SEQ);
}

// Round 3
// 238.281 us; speedup vs baseline: 1.2829x; 1.2829x over previous
//
#include <hip/hip_runtime.h>
#include <hip/hip_fp16.h>
#include <cstdint>

#define SEQ 4096
#define DIM 1024

typedef _Float16 f16x8 __attribute__((ext_vector_type(8)));
typedef float f32x4 __attribute__((ext_vector_type(4)));
typedef __attribute__((address_space(1))) void as1_void;
typedef __attribute__((address_space(3))) void as3_void;

__device__ __forceinline__ ushort f2h(float f) {
  _Float16 h = (_Float16)f;
  return __builtin_bit_cast(ushort, h);
}

// ---------------- conversions ----------------
__global__ void convert_x_kernel(const float* __restrict__ X, ushort* __restrict__ Xh, int n4) {
  int i = blockIdx.x * blockDim.x + threadIdx.x;
  if (i >= n4) return;
  float4 v = reinterpret_cast<const float4*>(X)[i];
  ushort4 o = { f2h(v.x), f2h(v.y), f2h(v.z), f2h(v.w) };
  reinterpret_cast<ushort4*>(Xh)[i] = o;
}

__global__ void convert_w_kernel(const float* __restrict__ Wk, const float* __restrict__ Wv,
                                 const float* __restrict__ Wq, ushort* __restrict__ Wt) {
  __shared__ float tile[32][33];
  int z = blockIdx.z;
  const float* W = (z == 0) ? Wk : (z == 1) ? Wv : Wq;
  int n0 = blockIdx.x * 32, k0 = blockIdx.y * 32;
  int tx = threadIdx.x, ty = threadIdx.y; // (32,8)
#pragma unroll
  for (int r = 0; r < 4; r++) {
    int k = ty + r * 8;
    tile[k][tx] = W[(size_t)(k0 + k) * DIM + n0 + tx];
  }
  __syncthreads();
  ushort* out = Wt + (size_t)z * DIM * DIM;
#pragma unroll
  for (int r = 0; r < 4; r++) {
    int n = ty + r * 8;
    out[(size_t)(n0 + n) * DIM + k0 + tx] = f2h(tile[tx][n]);
  }
}

// ---------------- core GEMM tile: C[m0..+128, n0..+128] += A[.,kt0..ktend] * Bt^T ----------------
// 128x128 tile, BK=64, 4 waves (2x2 of 64x64), 16x16x32 f16 MFMA.
// LDS staging via global_load_lds width=16 with XOR chunk swizzle:
//   LDS[r][cs] holds global chunk cs ^ (r&7); reader at (r, ca) uses cs = ca ^ (r&7).
//   -> each quad's 16 ds_read_b128 lanes spread over all 8 bank groups (2/bank = free).
template <bool F16_OUT>
__device__ __forceinline__ void gemm_tile(const ushort* __restrict__ A,
                                          const ushort* __restrict__ B,
                                          void* __restrict__ C,
                                          int N, int K, int m0, int n0,
                                          int kt0, int ktend) {
  constexpr int BK = 64;
  __shared__ __align__(16) ushort As[128 * BK];
  __shared__ __align__(16) ushort Bs[128 * BK];
  const int tid = threadIdx.x;
  const int wave = tid >> 6, lane = tid & 63;
  const int lane15 = lane & 15, quad = lane >> 4;
  const int wm = (wave & 1) * 64, wn = (wave >> 1) * 64;

  // staging: lane (tid) covers row srow(+q*32); fetches the global chunk that
  // belongs at its LDS slot under the XOR swizzle
  const int srow = tid >> 3;
  const int sce = (((tid & 7) ^ ((tid >> 3) & 7)) * 8);  // swizzled chunk, in elements
  const int rs = lane15 & 7;                             // read-side swizzle key

  f32x4 acc[4][4];
#pragma unroll
  for (int i = 0; i < 4; i++)
#pragma unroll
    for (int j = 0; j < 4; j++) {
      f32x4 z = {0.f, 0.f, 0.f, 0.f};
      acc[i][j] = z;
    }

  for (int kt = kt0; kt < ktend; kt += BK) {
    __syncthreads();
#pragma unroll
    for (int q = 0; q < 4; q++) {
      const ushort* ga = A + (size_t)(m0 + srow + q * 32) * K + kt + sce;
      __builtin_amdgcn_global_load_lds((const as1_void*)ga,
                                       (as3_void*)&As[wave * 512 + q * 2048], 16, 0, 0);
    }
#pragma unroll
    for (int q = 0; q < 4; q++) {
      const ushort* gb = B + (size_t)(n0 + srow + q * 32) * K + kt + sce;
      __builtin_amdgcn_global_load_lds((const as1_void*)gb,
                                       (as3_void*)&Bs[wave * 512 + q * 2048], 16, 0, 0);
    }
    __syncthreads();
#pragma unroll
    for (int ks = 0; ks < 2; ks++) {
      f16x8 af[4], bfr[4];
#pragma unroll
      for (int i = 0; i < 4; i++)
        af[i] = *reinterpret_cast<const f16x8*>(
            &As[(wm + i * 16 + lane15) * BK + (((ks * 4 + quad) ^ rs) * 8)]);
#pragma unroll
      for (int j = 0; j < 4; j++)
        bfr[j] = *reinterpret_cast<const f16x8*>(
            &Bs[(wn + j * 16 + lane15) * BK + (((ks * 4 + quad) ^ rs) * 8)]);
#pragma unroll
      for (int i = 0; i < 4; i++)
#pragma unroll
        for (int j = 0; j < 4; j++)
          acc[i][j] = __builtin_amdgcn_mfma_f32_16x16x32_f16(af[i], bfr[j], acc[i][j], 0, 0, 0);
    }
  }

  // epilogue: C/D layout col=lane&15, row=quad*4+reg  [m89-verified, dtype-independent]
  const int rbase = m0 + wm + quad * 4;
  const int cbase = n0 + wn + lane15;
#pragma unroll
  for (int i = 0; i < 4; i++)
#pragma unroll
    for (int j = 0; j < 4; j++)
#pragma unroll
      for (int r = 0; r < 4; r++) {
        int row = rbase + i * 16 + r;
        int col = cbase + j * 16;
        if (F16_OUT)
          reinterpret_cast<ushort*>(C)[(size_t)row * N + col] = f2h(acc[i][j][r]);
        else
          reinterpret_cast<float*>(C)[(size_t)row * N + col] = acc[i][j][r];
      }
}

// ---------------- fused K/Q/V^T projections (one dispatch, 768 blocks) ----------------
__global__ __launch_bounds__(256) void proj_kernel(const ushort* __restrict__ Xh,
                                                   const ushort* __restrict__ Wt,
                                                   ushort* __restrict__ Kh,
                                                   ushort* __restrict__ Qh,
                                                   ushort* __restrict__ Vt) {
  const int z = blockIdx.z;
  const ushort* A;
  const ushort* B;
  ushort* C;
  int N, m0, n0;
  if (z < 2) {
    // K or Q: [SEQ,DIM] = Xh @ W^T ; grid 256 = 32 (m) x 8 (n)
    A = Xh;
    B = Wt + (size_t)(z == 0 ? 0 : 2) * DIM * DIM;
    C = (z == 0) ? Kh : Qh;
    N = DIM;
    m0 = (blockIdx.x >> 3) * 128;
    n0 = (blockIdx.x & 7) * 128;
  } else {
    // V^T: [DIM,SEQ] = WvT @ Xh^T ; grid 256 = 8 (m) x 32 (n)
    A = Wt + (size_t)DIM * DIM;
    B = Xh;
    C = Vt;
    N = SEQ;
    m0 = (blockIdx.x >> 5) * 128;
    n0 = (blockIdx.x & 31) * 128;
  }
  gemm_tile<true>(A, B, C, N, DIM, m0, n0, 0, DIM);
}

// ---------------- S = K @ Q^T (fp32) ----------------
__global__ __launch_bounds__(256) void score_kernel(const ushort* __restrict__ Kh,
                                                    const ushort* __restrict__ Qh,
                                                    float* __restrict__ S) {
  gemm_tile<false>(Kh, Qh, S, SEQ, DIM, blockIdx.y * 128, blockIdx.x * 128, 0, DIM);
}

// ---------------- O partials: split-K=4 over SEQ ----------------
__global__ __launch_bounds__(256) void out_splitk_kernel(const ushort* __restrict__ P,
                                                         const ushort* __restrict__ Vt,
                                                         float* __restrict__ Part) {
  float* C = Part + (size_t)blockIdx.z * SEQ * DIM;
  gemm_tile<false>(P, Vt, C, DIM, SEQ, blockIdx.y * 128, blockIdx.x * 128,
                   blockIdx.z * (SEQ / 4), (blockIdx.z + 1) * (SEQ / 4));
}

__global__ void reduce4_kernel(const float* __restrict__ Part, float* __restrict__ out, int n4) {
  int i = blockIdx.x * blockDim.x + threadIdx.x;
  if (i >= n4) return;
  const float4* p0 = reinterpret_cast<const float4*>(Part);
  const float4* p1 = p0 + n4;
  const float4* p2 = p1 + n4;
  const float4* p3 = p2 + n4;
  float4 a = p0[i], b = p1[i], c = p2[i], d = p3[i];
  float4 r = { a.x + b.x + c.x + d.x, a.y + b.y + c.y + d.y,
               a.z + b.z + c.z + d.z, a.w + b.w + c.w + d.w };
  reinterpret_cast<float4*>(out)[i] = r;
}

// ---------------- row softmax: S (f32) -> P (fp16) ----------------
__global__ __launch_bounds__(256) void softmax_kernel(const float* __restrict__ S,
                                                      ushort* __restrict__ P) {
  const int row = blockIdx.x;
  const float* s = S + (size_t)row * SEQ;
  const int tid = threadIdx.x;
  const int wave = tid >> 6, lane = tid & 63;
  __shared__ float red[4];
  float v[16];
#pragma unroll
  for (int i = 0; i < 4; i++) {
    float4 f = reinterpret_cast<const float4*>(s)[tid + i * 256];
    v[i * 4 + 0] = f.x; v[i * 4 + 1] = f.y; v[i * 4 + 2] = f.z; v[i * 4 + 3] = f.w;
  }
  float m = v[0];
#pragma unroll
  for (int j = 1; j < 16; j++) m = fmaxf(m, v[j]);
#pragma unroll
  for (int o = 32; o > 0; o >>= 1) m = fmaxf(m, __shfl_xor(m, o, 64));
  if (lane == 0) red[wave] = m;
  __syncthreads();
  m = fmaxf(fmaxf(red[0], red[1]), fmaxf(red[2], red[3]));
  __syncthreads();
  float sum = 0.f;
#pragma unroll
  for (int j = 0; j < 16; j++) {
    v[j] = __expf(v[j] - m);
    sum += v[j];
  }
#pragma unroll
  for (int o = 32; o > 0; o >>= 1) sum += __shfl_xor(sum, o, 64);
  if (lane == 0) red[wave] = sum;
  __syncthreads();
  sum = red[0] + red[1] + red[2] + red[3];
  float inv = 1.0f / sum;
  ushort* p = P + (size_t)row * SEQ;
#pragma unroll
  for (int i = 0; i < 4; i++) {
    ushort4 o4 = { f2h(v[i * 4 + 0] * inv), f2h(v[i * 4 + 1] * inv),
                   f2h(v[i * 4 + 2] * inv), f2h(v[i * 4 + 3] * inv) };
    reinterpret_cast<ushort4*>(p)[tid + i * 256] = o4;
  }
}

extern "C" void kernel_launch(void* const* d_in, const int* in_sizes, int n_in,
                              void* d_out, int out_size, void* d_ws, size_t ws_size,
                              hipStream_t stream) {
  const float* X = (const float*)d_in[0];
  const float* Wk = (const float*)d_in[1];
  const float* Wv = (const float*)d_in[2];
  const float* Wq = (const float*)d_in[3];

  char* ws = (char*)d_ws;
  size_t off = 0;
  ushort* Xh = (ushort*)(ws + off); off += (size_t)SEQ * DIM * 2;      // 8 MB
  ushort* Wt = (ushort*)(ws + off); off += (size_t)3 * DIM * DIM * 2;  // 6 MB
  ushort* Kh = (ushort*)(ws + off); off += (size_t)SEQ * DIM * 2;      // 8 MB
  ushort* Qh = (ushort*)(ws + off); off += (size_t)SEQ * DIM * 2;      // 8 MB
  ushort* Vt = (ushort*)(ws + off); off += (size_t)SEQ * DIM * 2;      // 8 MB (V^T: DIM x SEQ)
  float* S = (float*)(ws + off);    off += (size_t)SEQ * SEQ * 4;      // 64 MB (reused as O partials)
  ushort* P = (ushort*)(ws + off);  off += (size_t)SEQ * SEQ * 2;      // 32 MB

  float* Part = S;  // 4 x [SEQ,DIM] fp32 partials alias S (both 67.1 MB); S dead after softmax

  convert_x_kernel<<<SEQ * DIM / 4 / 256, 256, 0, stream>>>(X, Xh, SEQ * DIM / 4);
  convert_w_kernel<<<dim3(DIM / 32, DIM / 32, 3), dim3(32, 8), 0, stream>>>(Wk, Wv, Wq, Wt);

  proj_kernel<<<dim3(256, 1, 3), 256, 0, stream>>>(Xh, Wt, Kh, Qh, Vt);
  score_kernel<<<dim3(SEQ / 128, SEQ / 128), 256, 0, stream>>>(Kh, Qh, S);
  softmax_kernel<<<SEQ, 256, 0, stream>>>(S, P);
  out_splitk_kernel<<<dim3(DIM / 128, SEQ / 128, 4), 256, 0, stream>>>(P, Vt, Part);
  reduce4_kernel<<<SEQ * DIM / 4 / 256, 256, 0, stream>>>(Part, (float*)d_out, SEQ * DIM / 4);
}

// Round 4
// 224.220 us; speedup vs baseline: 1.3633x; 1.0627x over previous
//
#include <hip/hip_runtime.h>
#include <hip/hip_fp16.h>
#include <cstdint>

#define SEQ 4096
#define DIM 1024

typedef _Float16 f16x8 __attribute__((ext_vector_type(8)));
typedef float f32x4 __attribute__((ext_vector_type(4)));
typedef __attribute__((address_space(1))) void as1_void;
typedef __attribute__((address_space(3))) void as3_void;

__device__ __forceinline__ ushort f2h(float f) {
  _Float16 h = (_Float16)f;
  return __builtin_bit_cast(ushort, h);
}

// ---------------- conversions ----------------
__global__ void convert_x_kernel(const float* __restrict__ X, ushort* __restrict__ Xh, int n4) {
  int i = blockIdx.x * blockDim.x + threadIdx.x;
  if (i >= n4) return;
  float4 v = reinterpret_cast<const float4*>(X)[i];
  ushort4 o = { f2h(v.x), f2h(v.y), f2h(v.z), f2h(v.w) };
  reinterpret_cast<ushort4*>(Xh)[i] = o;
}

__global__ void convert_w_kernel(const float* __restrict__ Wk, const float* __restrict__ Wv,
                                 const float* __restrict__ Wq, ushort* __restrict__ Wt) {
  __shared__ float tile[32][33];
  int z = blockIdx.z;
  const float* W = (z == 0) ? Wk : (z == 1) ? Wv : Wq;
  int n0 = blockIdx.x * 32, k0 = blockIdx.y * 32;
  int tx = threadIdx.x, ty = threadIdx.y; // (32,8)
#pragma unroll
  for (int r = 0; r < 4; r++) {
    int k = ty + r * 8;
    tile[k][tx] = W[(size_t)(k0 + k) * DIM + n0 + tx];
  }
  __syncthreads();
  ushort* out = Wt + (size_t)z * DIM * DIM;
#pragma unroll
  for (int r = 0; r < 4; r++) {
    int n = ty + r * 8;
    out[(size_t)(n0 + n) * DIM + k0 + tx] = f2h(tile[tx][n]);
  }
}

// ---------------- core GEMM tile ----------------
// 128x128 tile, BK=64, 4 waves (2x2 of 64x64), 16x16x32 f16 MFMA.
// LDS staging via global_load_lds width=16 with XOR chunk swizzle (R3: 0 bank conflicts).
template <bool F16_OUT>
__device__ __forceinline__ void gemm_tile(const ushort* __restrict__ A,
                                          const ushort* __restrict__ B,
                                          void* __restrict__ C,
                                          int N, int K, int m0, int n0,
                                          int kt0, int ktend) {
  constexpr int BK = 64;
  __shared__ __align__(16) ushort As[128 * BK];
  __shared__ __align__(16) ushort Bs[128 * BK];
  const int tid = threadIdx.x;
  const int wave = tid >> 6, lane = tid & 63;
  const int lane15 = lane & 15, quad = lane >> 4;
  const int wm = (wave & 1) * 64, wn = (wave >> 1) * 64;

  const int srow = tid >> 3;
  const int sce = (((tid & 7) ^ ((tid >> 3) & 7)) * 8);  // swizzled source chunk (elems)
  const int rs = lane15 & 7;                             // read-side swizzle key

  f32x4 acc[4][4];
#pragma unroll
  for (int i = 0; i < 4; i++)
#pragma unroll
    for (int j = 0; j < 4; j++) {
      f32x4 z = {0.f, 0.f, 0.f, 0.f};
      acc[i][j] = z;
    }

  for (int kt = kt0; kt < ktend; kt += BK) {
    __syncthreads();
#pragma unroll
    for (int q = 0; q < 4; q++) {
      const ushort* ga = A + (size_t)(m0 + srow + q * 32) * K + kt + sce;
      __builtin_amdgcn_global_load_lds((const as1_void*)ga,
                                       (as3_void*)&As[wave * 512 + q * 2048], 16, 0, 0);
    }
#pragma unroll
    for (int q = 0; q < 4; q++) {
      const ushort* gb = B + (size_t)(n0 + srow + q * 32) * K + kt + sce;
      __builtin_amdgcn_global_load_lds((const as1_void*)gb,
                                       (as3_void*)&Bs[wave * 512 + q * 2048], 16, 0, 0);
    }
    __syncthreads();
#pragma unroll
    for (int ks = 0; ks < 2; ks++) {
      f16x8 af[4], bfr[4];
#pragma unroll
      for (int i = 0; i < 4; i++)
        af[i] = *reinterpret_cast<const f16x8*>(
            &As[(wm + i * 16 + lane15) * BK + (((ks * 4 + quad) ^ rs) * 8)]);
#pragma unroll
      for (int j = 0; j < 4; j++)
        bfr[j] = *reinterpret_cast<const f16x8*>(
            &Bs[(wn + j * 16 + lane15) * BK + (((ks * 4 + quad) ^ rs) * 8)]);
#pragma unroll
      for (int i = 0; i < 4; i++)
#pragma unroll
        for (int j = 0; j < 4; j++)
          acc[i][j] = __builtin_amdgcn_mfma_f32_16x16x32_f16(af[i], bfr[j], acc[i][j], 0, 0, 0);
    }
  }

  // epilogue: C/D layout col=lane&15, row=quad*4+reg  [m89-verified]
  const int rbase = m0 + wm + quad * 4;
  const int cbase = n0 + wn + lane15;
#pragma unroll
  for (int i = 0; i < 4; i++)
#pragma unroll
    for (int j = 0; j < 4; j++)
#pragma unroll
      for (int r = 0; r < 4; r++) {
        int row = rbase + i * 16 + r;
        int col = cbase + j * 16;
        if (F16_OUT)
          reinterpret_cast<ushort*>(C)[(size_t)row * N + col] = f2h(acc[i][j][r]);
        else
          reinterpret_cast<float*>(C)[(size_t)row * N + col] = acc[i][j][r];
      }
}

// ---------------- fused K/Q/V^T projections ----------------
__global__ __launch_bounds__(256) void proj_kernel(const ushort* __restrict__ Xh,
                                                   const ushort* __restrict__ Wt,
                                                   ushort* __restrict__ Kh,
                                                   ushort* __restrict__ Qh,
                                                   ushort* __restrict__ Vt) {
  const int z = blockIdx.z;
  const ushort* A;
  const ushort* B;
  ushort* C;
  int N, m0, n0;
  if (z < 2) {
    A = Xh;
    B = Wt + (size_t)(z == 0 ? 0 : 2) * DIM * DIM;
    C = (z == 0) ? Kh : Qh;
    N = DIM;
    m0 = (blockIdx.x >> 3) * 128;
    n0 = (blockIdx.x & 7) * 128;
  } else {
    A = Wt + (size_t)DIM * DIM;
    B = Xh;
    C = Vt;
    N = SEQ;
    m0 = (blockIdx.x >> 5) * 128;
    n0 = (blockIdx.x & 31) * 128;
  }
  gemm_tile<true>(A, B, C, N, DIM, m0, n0, 0, DIM);
}

// ---------------- S = K @ Q^T (fp16 out), XCD-swizzled 8x8 supertiles ----------------
// f&7 -> XCD (round-robin dispatch assumption; perf-only). Each XCD gets a
// contiguous chunk of 128 tiles = two 8x8 supertiles (A 2MB + B 2MB = L2-sized).
__global__ __launch_bounds__(256) void score_kernel(const ushort* __restrict__ Kh,
                                                    const ushort* __restrict__ Qh,
                                                    ushort* __restrict__ S) {
  const int f = blockIdx.x;          // [0,1024)
  const int xcd = f & 7;
  const int r = f >> 3;              // [0,128)
  const int t = xcd * 128 + r;       // XCD-contiguous tile index
  const int st = t >> 6, within = t & 63;
  const int sx = within & 7, sy = within >> 3;
  const int tx = (st & 3) * 8 + sx;  // 4x4 supertile grid
  const int ty = (st >> 2) * 8 + sy;
  gemm_tile<true>(Kh, Qh, S, SEQ, DIM, ty * 128, tx * 128, 0, DIM);
}

// ---------------- O partials: split-K=4, fp16 partials, XCD-swizzled ----------------
__global__ __launch_bounds__(256) void out_splitk_kernel(const ushort* __restrict__ P,
                                                         const ushort* __restrict__ Vt,
                                                         ushort* __restrict__ Part) {
  const int f = blockIdx.x;          // [0,1024)
  const int z = f >> 8;              // split-K slice (slab-contiguous)
  const int q = f & 255;
  const int xcd = q & 7;
  const int r = q >> 3;              // [0,32)
  const int t = xcd * 32 + r;        // XCD-contiguous, row-major 8x4 chunk (3MB ws)
  const int tx = t & 7, ty = t >> 3;
  ushort* C = Part + (size_t)z * SEQ * DIM;
  gemm_tile<true>(P, Vt, C, DIM, SEQ, ty * 128, tx * 128,
                  z * (SEQ / 4), (z + 1) * (SEQ / 4));
}

__global__ void reduce4_kernel(const ushort* __restrict__ Part, float* __restrict__ out, int n8) {
  int i = blockIdx.x * blockDim.x + threadIdx.x;
  if (i >= n8) return;
  const f16x8* p0 = reinterpret_cast<const f16x8*>(Part);
  const f16x8* p1 = p0 + n8;
  const f16x8* p2 = p1 + n8;
  const f16x8* p3 = p2 + n8;
  f16x8 a = p0[i], b = p1[i], c = p2[i], d = p3[i];
  float4 lo, hi;
  lo.x = (float)a[0] + (float)b[0] + (float)c[0] + (float)d[0];
  lo.y = (float)a[1] + (float)b[1] + (float)c[1] + (float)d[1];
  lo.z = (float)a[2] + (float)b[2] + (float)c[2] + (float)d[2];
  lo.w = (float)a[3] + (float)b[3] + (float)c[3] + (float)d[3];
  hi.x = (float)a[4] + (float)b[4] + (float)c[4] + (float)d[4];
  hi.y = (float)a[5] + (float)b[5] + (float)c[5] + (float)d[5];
  hi.z = (float)a[6] + (float)b[6] + (float)c[6] + (float)d[6];
  hi.w = (float)a[7] + (float)b[7] + (float)c[7] + (float)d[7];
  reinterpret_cast<float4*>(out)[i * 2] = lo;
  reinterpret_cast<float4*>(out)[i * 2 + 1] = hi;
}

// ---------------- row softmax: S (fp16) -> P (fp16) ----------------
__global__ __launch_bounds__(256) void softmax_kernel(const ushort* __restrict__ S,
                                                      ushort* __restrict__ P) {
  const int row = blockIdx.x;
  const ushort* s = S + (size_t)row * SEQ;
  const int tid = threadIdx.x;
  const int wave = tid >> 6, lane = tid & 63;
  __shared__ float red[4];
  float v[16];
#pragma unroll
  for (int i = 0; i < 2; i++) {
    f16x8 h = reinterpret_cast<const f16x8*>(s)[tid + i * 256];
#pragma unroll
    for (int j = 0; j < 8; j++) v[i * 8 + j] = (float)h[j];
  }
  float m = v[0];
#pragma unroll
  for (int j = 1; j < 16; j++) m = fmaxf(m, v[j]);
#pragma unroll
  for (int o = 32; o > 0; o >>= 1) m = fmaxf(m, __shfl_xor(m, o, 64));
  if (lane == 0) red[wave] = m;
  __syncthreads();
  m = fmaxf(fmaxf(red[0], red[1]), fmaxf(red[2], red[3]));
  __syncthreads();
  float sum = 0.f;
#pragma unroll
  for (int j = 0; j < 16; j++) {
    v[j] = __expf(v[j] - m);
    sum += v[j];
  }
#pragma unroll
  for (int o = 32; o > 0; o >>= 1) sum += __shfl_xor(sum, o, 64);
  if (lane == 0) red[wave] = sum;
  __syncthreads();
  sum = red[0] + red[1] + red[2] + red[3];
  float inv = 1.0f / sum;
  ushort* p = P + (size_t)row * SEQ;
#pragma unroll
  for (int i = 0; i < 2; i++) {
    ushort4 o4a = { f2h(v[i * 8 + 0] * inv), f2h(v[i * 8 + 1] * inv),
                    f2h(v[i * 8 + 2] * inv), f2h(v[i * 8 + 3] * inv) };
    ushort4 o4b = { f2h(v[i * 8 + 4] * inv), f2h(v[i * 8 + 5] * inv),
                    f2h(v[i * 8 + 6] * inv), f2h(v[i * 8 + 7] * inv) };
    reinterpret_cast<ushort4*>(p)[(tid + i * 256) * 2] = o4a;
    reinterpret_cast<ushort4*>(p)[(tid + i * 256) * 2 + 1] = o4b;
  }
}

extern "C" void kernel_launch(void* const* d_in, const int* in_sizes, int n_in,
                              void* d_out, int out_size, void* d_ws, size_t ws_size,
                              hipStream_t stream) {
  const float* X = (const float*)d_in[0];
  const float* Wk = (const float*)d_in[1];
  const float* Wv = (const float*)d_in[2];
  const float* Wq = (const float*)d_in[3];

  char* ws = (char*)d_ws;
  size_t off = 0;
  ushort* Xh = (ushort*)(ws + off); off += (size_t)SEQ * DIM * 2;      // 8 MB
  ushort* Wt = (ushort*)(ws + off); off += (size_t)3 * DIM * DIM * 2;  // 6 MB
  ushort* Kh = (ushort*)(ws + off); off += (size_t)SEQ * DIM * 2;      // 8 MB
  ushort* Qh = (ushort*)(ws + off); off += (size_t)SEQ * DIM * 2;      // 8 MB
  ushort* Vt = (ushort*)(ws + off); off += (size_t)SEQ * DIM * 2;      // 8 MB
  ushort* S = (ushort*)(ws + off);  off += (size_t)SEQ * SEQ * 2;      // 32 MB (fp16; reused as partials)
  ushort* P = (ushort*)(ws + off);  off += (size_t)SEQ * SEQ * 2;      // 32 MB

  ushort* Part = S;  // 4 x [SEQ,DIM] fp16 partials (32 MB) alias S; S dead after softmax

  convert_x_kernel<<<SEQ * DIM / 4 / 256, 256, 0, stream>>>(X, Xh, SEQ * DIM / 4);
  convert_w_kernel<<<dim3(DIM / 32, DIM / 32, 3), dim3(32, 8), 0, stream>>>(Wk, Wv, Wq, Wt);

  proj_kernel<<<dim3(256, 1, 3), 256, 0, stream>>>(Xh, Wt, Kh, Qh, Vt);
  score_kernel<<<1024, 256, 0, stream>>>(Kh, Qh, S);
  softmax_kernel<<<SEQ, 256, 0, stream>>>(S, P);
  out_splitk_kernel<<<1024, 256, 0, stream>>>(P, Vt, Part);
  reduce4_kernel<<<SEQ * DIM / 8 / 256, 256, 0, stream>>>(Part, (float*)d_out, SEQ * DIM / 8);
}

// Round 5
// 211.042 us; speedup vs baseline: 1.4484x; 1.0624x over previous
//
#include <hip/hip_runtime.h>
#include <hip/hip_fp16.h>
#include <cstdint>

#define SEQ 4096
#define DIM 1024

typedef _Float16 f16x8 __attribute__((ext_vector_type(8)));
typedef float f32x16 __attribute__((ext_vector_type(16)));
typedef __attribute__((address_space(1))) void as1_void;
typedef __attribute__((address_space(3))) void as3_void;

__device__ __forceinline__ ushort f2h(float f) {
  _Float16 h = (_Float16)f;
  return __builtin_bit_cast(ushort, h);
}

// ---------------- fused conversions: z<3 -> W transpose+cvt, z==3 -> X cvt ----------------
__global__ void convert_all_kernel(const float* __restrict__ X, const float* __restrict__ Wk,
                                   const float* __restrict__ Wv, const float* __restrict__ Wq,
                                   ushort* __restrict__ Xh, ushort* __restrict__ Wt) {
  const int z = blockIdx.z;
  const int tx = threadIdx.x, ty = threadIdx.y;  // (32,8)
  if (z == 3) {
    // X: 4M elems, 1024 blocks in this slice, each 1024 float4
    const int bid = blockIdx.y * 32 + blockIdx.x;
    const int t = ty * 32 + tx;
#pragma unroll
    for (int k = 0; k < 4; k++) {
      int i = bid * 1024 + k * 256 + t;
      float4 v = reinterpret_cast<const float4*>(X)[i];
      ushort4 o = { f2h(v.x), f2h(v.y), f2h(v.z), f2h(v.w) };
      reinterpret_cast<ushort4*>(Xh)[i] = o;
    }
    return;
  }
  __shared__ float tile[32][33];
  const float* W = (z == 0) ? Wk : (z == 1) ? Wv : Wq;
  int n0 = blockIdx.x * 32, k0 = blockIdx.y * 32;
#pragma unroll
  for (int r = 0; r < 4; r++) {
    int k = ty + r * 8;
    tile[k][tx] = W[(size_t)(k0 + k) * DIM + n0 + tx];
  }
  __syncthreads();
  ushort* out = Wt + (size_t)z * DIM * DIM;
#pragma unroll
  for (int r = 0; r < 4; r++) {
    int n = ty + r * 8;
    out[(size_t)(n0 + n) * DIM + k0 + tx] = f2h(tile[tx][n]);
  }
}

// ---------------- core GEMM tile ----------------
// 128x128 tile, BK=64, 4 waves (2x2 of 64x64), 32x32x16 f16 MFMA (2x2 of 32x32/wave).
// LDS staging via global_load_lds width=16, XOR chunk swizzle with extended key
//   key(r) = (r&7) ^ ((r>>3)&3)   [invariant under r+32 and wave-tile offsets]
// -> every 16-lane ds_read_b128 phase covers all 8 chunk cols 2x (2-way = free).
template <bool F16_OUT>
__device__ __forceinline__ void gemm_tile(const ushort* __restrict__ A,
                                          const ushort* __restrict__ B,
                                          void* __restrict__ C,
                                          int N, int K, int m0, int n0,
                                          int kt0, int ktend) {
  constexpr int BK = 64;
  __shared__ __align__(16) ushort As[128 * BK];
  __shared__ __align__(16) ushort Bs[128 * BK];
  const int tid = threadIdx.x;
  const int wave = tid >> 6, lane = tid & 63;
  const int l31 = lane & 31, khalf = lane >> 5;
  const int wm = (wave & 1) * 64, wn = (wave >> 1) * 64;

  // staging: lane covers row srow(+q*32); source chunk = slot ^ key(row)
  const int srow = tid >> 3;
  const int skey = ((srow & 7) ^ ((srow >> 3) & 3));
  const int sce = (((tid & 7) ^ skey) * 8);
  // read-side key (row = wm/wn + mi*32 + l31; offsets are multiples of 32 -> drop out)
  const int rk = (l31 & 7) ^ ((l31 >> 3) & 3);

  f32x16 acc[2][2];
#pragma unroll
  for (int i = 0; i < 2; i++)
#pragma unroll
    for (int j = 0; j < 2; j++)
#pragma unroll
      for (int r = 0; r < 16; r++) acc[i][j][r] = 0.f;

  for (int kt = kt0; kt < ktend; kt += BK) {
    __syncthreads();
#pragma unroll
    for (int q = 0; q < 4; q++) {
      const ushort* ga = A + (size_t)(m0 + srow + q * 32) * K + kt + sce;
      __builtin_amdgcn_global_load_lds((const as1_void*)ga,
                                       (as3_void*)&As[wave * 512 + q * 2048], 16, 0, 0);
    }
#pragma unroll
    for (int q = 0; q < 4; q++) {
      const ushort* gb = B + (size_t)(n0 + srow + q * 32) * K + kt + sce;
      __builtin_amdgcn_global_load_lds((const as1_void*)gb,
                                       (as3_void*)&Bs[wave * 512 + q * 2048], 16, 0, 0);
    }
    __syncthreads();
#pragma unroll
    for (int ks = 0; ks < 4; ks++) {
      f16x8 af[2], bfr[2];
      const int ck = (ks * 2 + khalf);
#pragma unroll
      for (int i = 0; i < 2; i++)
        af[i] = *reinterpret_cast<const f16x8*>(
            &As[(wm + i * 32 + l31) * BK + ((ck ^ rk) * 8)]);
#pragma unroll
      for (int j = 0; j < 2; j++)
        bfr[j] = *reinterpret_cast<const f16x8*>(
            &Bs[(wn + j * 32 + l31) * BK + ((ck ^ rk) * 8)]);
#pragma unroll
      for (int i = 0; i < 2; i++)
#pragma unroll
        for (int j = 0; j < 2; j++)
          acc[i][j] = __builtin_amdgcn_mfma_f32_32x32x16_f16(af[i], bfr[j], acc[i][j], 0, 0, 0);
    }
  }

  // epilogue: 32x32 C/D layout col=lane&31, row=(reg&3)+8*(reg>>2)+4*(lane>>5)  [m74/m101]
#pragma unroll
  for (int i = 0; i < 2; i++)
#pragma unroll
    for (int j = 0; j < 2; j++)
#pragma unroll
      for (int r = 0; r < 16; r++) {
        int row = m0 + wm + i * 32 + (r & 3) + 8 * (r >> 2) + 4 * khalf;
        int col = n0 + wn + j * 32 + l31;
        if (F16_OUT)
          reinterpret_cast<ushort*>(C)[(size_t)row * N + col] = f2h(acc[i][j][r]);
        else
          reinterpret_cast<float*>(C)[(size_t)row * N + col] = acc[i][j][r];
      }
}

// ---------------- fused K/Q/V^T projections ----------------
__global__ __launch_bounds__(256) void proj_kernel(const ushort* __restrict__ Xh,
                                                   const ushort* __restrict__ Wt,
                                                   ushort* __restrict__ Kh,
                                                   ushort* __restrict__ Qh,
                                                   ushort* __restrict__ Vt) {
  const int z = blockIdx.z;
  const ushort* A;
  const ushort* B;
  ushort* C;
  int N, m0, n0;
  if (z < 2) {
    A = Xh;
    B = Wt + (size_t)(z == 0 ? 0 : 2) * DIM * DIM;
    C = (z == 0) ? Kh : Qh;
    N = DIM;
    m0 = (blockIdx.x >> 3) * 128;
    n0 = (blockIdx.x & 7) * 128;
  } else {
    A = Wt + (size_t)DIM * DIM;
    B = Xh;
    C = Vt;
    N = SEQ;
    m0 = (blockIdx.x >> 5) * 128;
    n0 = (blockIdx.x & 31) * 128;
  }
  gemm_tile<true>(A, B, C, N, DIM, m0, n0, 0, DIM);
}

// ---------------- S = K @ Q^T (fp16 out), XCD-swizzled 8x8 supertiles ----------------
__global__ __launch_bounds__(256) void score_kernel(const ushort* __restrict__ Kh,
                                                    const ushort* __restrict__ Qh,
                                                    ushort* __restrict__ S) {
  const int f = blockIdx.x;          // [0,1024)
  const int xcd = f & 7;
  const int r = f >> 3;              // [0,128)
  const int t = xcd * 128 + r;       // XCD-contiguous tile index
  const int st = t >> 6, within = t & 63;
  const int sx = within & 7, sy = within >> 3;
  const int tx = (st & 3) * 8 + sx;
  const int ty = (st >> 2) * 8 + sy;
  gemm_tile<true>(Kh, Qh, S, SEQ, DIM, ty * 128, tx * 128, 0, DIM);
}

// ---------------- O partials: split-K=4, fp16 partials, XCD-swizzled ----------------
__global__ __launch_bounds__(256) void out_splitk_kernel(const ushort* __restrict__ P,
                                                         const ushort* __restrict__ Vt,
                                                         ushort* __restrict__ Part) {
  const int f = blockIdx.x;          // [0,1024)
  const int z = f >> 8;
  const int q = f & 255;
  const int xcd = q & 7;
  const int r = q >> 3;
  const int t = xcd * 32 + r;
  const int tx = t & 7, ty = t >> 3;
  ushort* C = Part + (size_t)z * SEQ * DIM;
  gemm_tile<true>(P, Vt, C, DIM, SEQ, ty * 128, tx * 128,
                  z * (SEQ / 4), (z + 1) * (SEQ / 4));
}

__global__ void reduce4_kernel(const ushort* __restrict__ Part, float* __restrict__ out, int n8) {
  int i = blockIdx.x * blockDim.x + threadIdx.x;
  if (i >= n8) return;
  const f16x8* p0 = reinterpret_cast<const f16x8*>(Part);
  const f16x8* p1 = p0 + n8;
  const f16x8* p2 = p1 + n8;
  const f16x8* p3 = p2 + n8;
  f16x8 a = p0[i], b = p1[i], c = p2[i], d = p3[i];
  float4 lo, hi;
  lo.x = (float)a[0] + (float)b[0] + (float)c[0] + (float)d[0];
  lo.y = (float)a[1] + (float)b[1] + (float)c[1] + (float)d[1];
  lo.z = (float)a[2] + (float)b[2] + (float)c[2] + (float)d[2];
  lo.w = (float)a[3] + (float)b[3] + (float)c[3] + (float)d[3];
  hi.x = (float)a[4] + (float)b[4] + (float)c[4] + (float)d[4];
  hi.y = (float)a[5] + (float)b[5] + (float)c[5] + (float)d[5];
  hi.z = (float)a[6] + (float)b[6] + (float)c[6] + (float)d[6];
  hi.w = (float)a[7] + (float)b[7] + (float)c[7] + (float)d[7];
  reinterpret_cast<float4*>(out)[i * 2] = lo;
  reinterpret_cast<float4*>(out)[i * 2 + 1] = hi;
}

// ---------------- row softmax: one wave per row, no LDS/barriers ----------------
__global__ __launch_bounds__(256) void softmax_kernel(const ushort* __restrict__ S,
                                                      ushort* __restrict__ P) {
  const int wave = threadIdx.x >> 6, lane = threadIdx.x & 63;
  const int row = blockIdx.x * 4 + wave;
  const ushort* s = S + (size_t)row * SEQ;
  float v[64];
#pragma unroll
  for (int i = 0; i < 8; i++) {
    f16x8 h = reinterpret_cast<const f16x8*>(s)[i * 64 + lane];
#pragma unroll
    for (int j = 0; j < 8; j++) v[i * 8 + j] = (float)h[j];
  }
  float m = v[0];
#pragma unroll
  for (int j = 1; j < 64; j++) m = fmaxf(m, v[j]);
#pragma unroll
  for (int o = 32; o > 0; o >>= 1) m = fmaxf(m, __shfl_xor(m, o, 64));
  float sum = 0.f;
#pragma unroll
  for (int j = 0; j < 64; j++) {
    v[j] = __expf(v[j] - m);
    sum += v[j];
  }
#pragma unroll
  for (int o = 32; o > 0; o >>= 1) sum += __shfl_xor(sum, o, 64);
  float inv = 1.0f / sum;
  ushort* p = P + (size_t)row * SEQ;
#pragma unroll
  for (int i = 0; i < 8; i++) {
    f16x8 h;
#pragma unroll
    for (int j = 0; j < 8; j++) h[j] = (_Float16)(v[i * 8 + j] * inv);
    reinterpret_cast<f16x8*>(p)[i * 64 + lane] = h;
  }
}

extern "C" void kernel_launch(void* const* d_in, const int* in_sizes, int n_in,
                              void* d_out, int out_size, void* d_ws, size_t ws_size,
                              hipStream_t stream) {
  const float* X = (const float*)d_in[0];
  const float* Wk = (const float*)d_in[1];
  const float* Wv = (const float*)d_in[2];
  const float* Wq = (const float*)d_in[3];

  char* ws = (char*)d_ws;
  size_t off = 0;
  ushort* Xh = (ushort*)(ws + off); off += (size_t)SEQ * DIM * 2;      // 8 MB
  ushort* Wt = (ushort*)(ws + off); off += (size_t)3 * DIM * DIM * 2;  // 6 MB
  ushort* Kh = (ushort*)(ws + off); off += (size_t)SEQ * DIM * 2;      // 8 MB
  ushort* Qh = (ushort*)(ws + off); off += (size_t)SEQ * DIM * 2;      // 8 MB
  ushort* Vt = (ushort*)(ws + off); off += (size_t)SEQ * DIM * 2;      // 8 MB
  ushort* S = (ushort*)(ws + off);  off += (size_t)SEQ * SEQ * 2;      // 32 MB (fp16; reused as partials)
  ushort* P = (ushort*)(ws + off);  off += (size_t)SEQ * SEQ * 2;      // 32 MB

  ushort* Part = S;  // 4 x [SEQ,DIM] fp16 partials alias S; S dead after softmax

  convert_all_kernel<<<dim3(32, 32, 4), dim3(32, 8), 0, stream>>>(X, Wk, Wv, Wq, Xh, Wt);
  proj_kernel<<<dim3(256, 1, 3), 256, 0, stream>>>(Xh, Wt, Kh, Qh, Vt);
  score_kernel<<<1024, 256, 0, stream>>>(Kh, Qh, S);
  softmax_kernel<<<1024, 256, 0, stream>>>(S, P);
  out_splitk_kernel<<<1024, 256, 0, stream>>>(P, Vt, Part);
  reduce4_kernel<<<SEQ * DIM / 8 / 256, 256, 0, stream>>>(Part, (float*)d_out, SEQ * DIM / 8);
}

// Round 6
// 203.163 us; speedup vs baseline: 1.5046x; 1.0388x over previous
//
#include <hip/hip_runtime.h>
#include <hip/hip_fp16.h>
#include <cstdint>

#define SEQ 4096
#define DIM 1024

typedef _Float16 f16x8 __attribute__((ext_vector_type(8)));
typedef float f32x16 __attribute__((ext_vector_type(16)));
typedef __attribute__((address_space(1))) void as1_void;
typedef __attribute__((address_space(3))) void as3_void;

__device__ __forceinline__ ushort f2h(float f) {
  _Float16 h = (_Float16)f;
  return __builtin_bit_cast(ushort, h);
}

// ---------------- fused conversions: z<3 -> W transpose+cvt, z==3 -> X cvt ----------------
__global__ void convert_all_kernel(const float* __restrict__ X, const float* __restrict__ Wk,
                                   const float* __restrict__ Wv, const float* __restrict__ Wq,
                                   ushort* __restrict__ Xh, ushort* __restrict__ Wt) {
  const int z = blockIdx.z;
  const int tx = threadIdx.x, ty = threadIdx.y;  // (32,8)
  if (z == 3) {
    const int bid = blockIdx.y * 32 + blockIdx.x;
    const int t = ty * 32 + tx;
#pragma unroll
    for (int k = 0; k < 4; k++) {
      int i = bid * 1024 + k * 256 + t;
      float4 v = reinterpret_cast<const float4*>(X)[i];
      ushort4 o = { f2h(v.x), f2h(v.y), f2h(v.z), f2h(v.w) };
      reinterpret_cast<ushort4*>(Xh)[i] = o;
    }
    return;
  }
  __shared__ float tile[32][33];
  const float* W = (z == 0) ? Wk : (z == 1) ? Wv : Wq;
  int n0 = blockIdx.x * 32, k0 = blockIdx.y * 32;
#pragma unroll
  for (int r = 0; r < 4; r++) {
    int k = ty + r * 8;
    tile[k][tx] = W[(size_t)(k0 + k) * DIM + n0 + tx];
  }
  __syncthreads();
  ushort* out = Wt + (size_t)z * DIM * DIM;
#pragma unroll
  for (int r = 0; r < 4; r++) {
    int n = ty + r * 8;
    out[(size_t)(n0 + n) * DIM + k0 + tx] = f2h(tile[tx][n]);
  }
}

// ---------------- core GEMM tile A: 128x128 block, 64x64/wave (proj) ----------------
// XOR chunk swizzle key(r) = (r&7) ^ ((r>>3)&3); verified 0 bank conflicts (R4/R5).
template <bool F16_OUT>
__device__ __forceinline__ void gemm_tile(const ushort* __restrict__ A,
                                          const ushort* __restrict__ B,
                                          void* __restrict__ C,
                                          int N, int K, int m0, int n0,
                                          int kt0, int ktend) {
  constexpr int BK = 64;
  __shared__ __align__(16) ushort As[128 * BK];
  __shared__ __align__(16) ushort Bs[128 * BK];
  const int tid = threadIdx.x;
  const int wave = tid >> 6, lane = tid & 63;
  const int l31 = lane & 31, khalf = lane >> 5;
  const int wm = (wave & 1) * 64, wn = (wave >> 1) * 64;

  const int srow = tid >> 3;
  const int skey = ((srow & 7) ^ ((srow >> 3) & 3));
  const int sce = (((tid & 7) ^ skey) * 8);
  const int rk = (l31 & 7) ^ ((l31 >> 3) & 3);

  f32x16 acc[2][2];
#pragma unroll
  for (int i = 0; i < 2; i++)
#pragma unroll
    for (int j = 0; j < 2; j++)
#pragma unroll
      for (int r = 0; r < 16; r++) acc[i][j][r] = 0.f;

  for (int kt = kt0; kt < ktend; kt += BK) {
    __syncthreads();
#pragma unroll
    for (int q = 0; q < 4; q++) {
      const ushort* ga = A + (size_t)(m0 + srow + q * 32) * K + kt + sce;
      __builtin_amdgcn_global_load_lds((const as1_void*)ga,
                                       (as3_void*)&As[wave * 512 + q * 2048], 16, 0, 0);
    }
#pragma unroll
    for (int q = 0; q < 4; q++) {
      const ushort* gb = B + (size_t)(n0 + srow + q * 32) * K + kt + sce;
      __builtin_amdgcn_global_load_lds((const as1_void*)gb,
                                       (as3_void*)&Bs[wave * 512 + q * 2048], 16, 0, 0);
    }
    __syncthreads();
#pragma unroll
    for (int ks = 0; ks < 4; ks++) {
      f16x8 af[2], bfr[2];
      const int ck = (ks * 2 + khalf);
#pragma unroll
      for (int i = 0; i < 2; i++)
        af[i] = *reinterpret_cast<const f16x8*>(
            &As[(wm + i * 32 + l31) * BK + ((ck ^ rk) * 8)]);
#pragma unroll
      for (int j = 0; j < 2; j++)
        bfr[j] = *reinterpret_cast<const f16x8*>(
            &Bs[(wn + j * 32 + l31) * BK + ((ck ^ rk) * 8)]);
#pragma unroll
      for (int i = 0; i < 2; i++)
#pragma unroll
        for (int j = 0; j < 2; j++)
          acc[i][j] = __builtin_amdgcn_mfma_f32_32x32x16_f16(af[i], bfr[j], acc[i][j], 0, 0, 0);
    }
  }

  // epilogue: 32x32 C/D layout col=lane&31, row=(reg&3)+8*(reg>>2)+4*(lane>>5)  [m74/m101]
#pragma unroll
  for (int i = 0; i < 2; i++)
#pragma unroll
    for (int j = 0; j < 2; j++)
#pragma unroll
      for (int r = 0; r < 16; r++) {
        int row = m0 + wm + i * 32 + (r & 3) + 8 * (r >> 2) + 4 * khalf;
        int col = n0 + wn + j * 32 + l31;
        if (F16_OUT)
          reinterpret_cast<ushort*>(C)[(size_t)row * N + col] = f2h(acc[i][j][r]);
        else
          reinterpret_cast<float*>(C)[(size_t)row * N + col] = acc[i][j][r];
      }
}

// ---------------- core GEMM tile B: 128x256 block, 64x128/wave (score/out) ----------------
// 32 MFMA per wave per barrier-pair (2x the A-variant) to amortize the vmcnt(0)
// barrier drain; 48KB LDS, ~2 blocks/CU — the AITER operating point.
__device__ __forceinline__ void gemm_tile_w128(const ushort* __restrict__ A,
                                               const ushort* __restrict__ B,
                                               ushort* __restrict__ C,
                                               int N, int K, int m0, int n0,
                                               int kt0, int ktend) {
  constexpr int BK = 64;
  __shared__ __align__(16) ushort As[128 * BK];   // 16 KB
  __shared__ __align__(16) ushort Bs[256 * BK];   // 32 KB
  const int tid = threadIdx.x;
  const int wave = tid >> 6, lane = tid & 63;
  const int l31 = lane & 31, khalf = lane >> 5;
  const int wm = (wave & 1) * 64, wn = (wave >> 1) * 128;

  const int srow = tid >> 3;
  const int skey = ((srow & 7) ^ ((srow >> 3) & 3));
  const int sce = (((tid & 7) ^ skey) * 8);
  const int rk = (l31 & 7) ^ ((l31 >> 3) & 3);

  f32x16 acc[2][4];
#pragma unroll
  for (int i = 0; i < 2; i++)
#pragma unroll
    for (int j = 0; j < 4; j++)
#pragma unroll
      for (int r = 0; r < 16; r++) acc[i][j][r] = 0.f;

  for (int kt = kt0; kt < ktend; kt += BK) {
    __syncthreads();
#pragma unroll
    for (int q = 0; q < 4; q++) {
      const ushort* ga = A + (size_t)(m0 + srow + q * 32) * K + kt + sce;
      __builtin_amdgcn_global_load_lds((const as1_void*)ga,
                                       (as3_void*)&As[wave * 512 + q * 2048], 16, 0, 0);
    }
#pragma unroll
    for (int q = 0; q < 8; q++) {
      const ushort* gb = B + (size_t)(n0 + srow + q * 32) * K + kt + sce;
      __builtin_amdgcn_global_load_lds((const as1_void*)gb,
                                       (as3_void*)&Bs[wave * 512 + q * 2048], 16, 0, 0);
    }
    __syncthreads();
#pragma unroll
    for (int ks = 0; ks < 4; ks++) {
      f16x8 af[2], bfr[4];
      const int ck = (ks * 2 + khalf);
#pragma unroll
      for (int i = 0; i < 2; i++)
        af[i] = *reinterpret_cast<const f16x8*>(
            &As[(wm + i * 32 + l31) * BK + ((ck ^ rk) * 8)]);
#pragma unroll
      for (int j = 0; j < 4; j++)
        bfr[j] = *reinterpret_cast<const f16x8*>(
            &Bs[(wn + j * 32 + l31) * BK + ((ck ^ rk) * 8)]);
#pragma unroll
      for (int i = 0; i < 2; i++)
#pragma unroll
        for (int j = 0; j < 4; j++)
          acc[i][j] = __builtin_amdgcn_mfma_f32_32x32x16_f16(af[i], bfr[j], acc[i][j], 0, 0, 0);
    }
  }

#pragma unroll
  for (int i = 0; i < 2; i++)
#pragma unroll
    for (int j = 0; j < 4; j++)
#pragma unroll
      for (int r = 0; r < 16; r++) {
        int row = m0 + wm + i * 32 + (r & 3) + 8 * (r >> 2) + 4 * khalf;
        int col = n0 + wn + j * 32 + l31;
        C[(size_t)row * N + col] = f2h(acc[i][j][r]);
      }
}

// ---------------- fused K/Q/V^T projections (768 blocks, tile A) ----------------
__global__ __launch_bounds__(256) void proj_kernel(const ushort* __restrict__ Xh,
                                                   const ushort* __restrict__ Wt,
                                                   ushort* __restrict__ Kh,
                                                   ushort* __restrict__ Qh,
                                                   ushort* __restrict__ Vt) {
  const int z = blockIdx.z;
  const ushort* A;
  const ushort* B;
  ushort* C;
  int N, m0, n0;
  if (z < 2) {
    A = Xh;
    B = Wt + (size_t)(z == 0 ? 0 : 2) * DIM * DIM;
    C = (z == 0) ? Kh : Qh;
    N = DIM;
    m0 = (blockIdx.x >> 3) * 128;
    n0 = (blockIdx.x & 7) * 128;
  } else {
    A = Wt + (size_t)DIM * DIM;
    B = Xh;
    C = Vt;
    N = SEQ;
    m0 = (blockIdx.x >> 5) * 128;
    n0 = (blockIdx.x & 31) * 128;
  }
  gemm_tile<true>(A, B, C, N, DIM, m0, n0, 0, DIM);
}

// ---------------- S = K @ Q^T (fp16), 128x256 tiles, XCD-swizzled ----------------
__global__ __launch_bounds__(256, 2) void score_kernel(const ushort* __restrict__ Kh,
                                                       const ushort* __restrict__ Qh,
                                                       ushort* __restrict__ S) {
  const int f = blockIdx.x;          // [0,512)
  const int xcd = f & 7;
  const int r = f >> 3;              // [0,64)
  const int t = xcd * 64 + r;        // XCD-contiguous
  const int within = t & 63, st = t >> 6;   // 8x8 supertile, st in [0,8)
  const int sx = within & 7, sy = within >> 3;
  const int tx = (st & 1) * 8 + sx;  // n-tile [0,16)
  const int ty = (st >> 1) * 8 + sy; // m-tile [0,32)
  gemm_tile_w128(Kh, Qh, S, SEQ, DIM, ty * 128, tx * 256, 0, DIM);
}

// ---------------- O partials: split-K=4, 128x256 tiles, fp16, XCD-swizzled ----------------
__global__ __launch_bounds__(256, 2) void out_splitk_kernel(const ushort* __restrict__ P,
                                                            const ushort* __restrict__ Vt,
                                                            ushort* __restrict__ Part) {
  const int f = blockIdx.x;          // [0,512)
  const int z = f >> 7;              // split slice
  const int q = f & 127;
  const int xcd = q & 7;
  const int r = q >> 3;              // [0,16)
  const int t = xcd * 16 + r;        // [0,128)
  const int tx = t & 3, ty = t >> 2; // n-tile [0,4), m-tile [0,32)
  ushort* C = Part + (size_t)z * SEQ * DIM;
  gemm_tile_w128(P, Vt, C, DIM, SEQ, ty * 128, tx * 256,
                 z * (SEQ / 4), (z + 1) * (SEQ / 4));
}

__global__ void reduce4_kernel(const ushort* __restrict__ Part, float* __restrict__ out, int n8) {
  int i = blockIdx.x * blockDim.x + threadIdx.x;
  if (i >= n8) return;
  const f16x8* p0 = reinterpret_cast<const f16x8*>(Part);
  const f16x8* p1 = p0 + n8;
  const f16x8* p2 = p1 + n8;
  const f16x8* p3 = p2 + n8;
  f16x8 a = p0[i], b = p1[i], c = p2[i], d = p3[i];
  float4 lo, hi;
  lo.x = (float)a[0] + (float)b[0] + (float)c[0] + (float)d[0];
  lo.y = (float)a[1] + (float)b[1] + (float)c[1] + (float)d[1];
  lo.z = (float)a[2] + (float)b[2] + (float)c[2] + (float)d[2];
  lo.w = (float)a[3] + (float)b[3] + (float)c[3] + (float)d[3];
  hi.x = (float)a[4] + (float)b[4] + (float)c[4] + (float)d[4];
  hi.y = (float)a[5] + (float)b[5] + (float)c[5] + (float)d[5];
  hi.z = (float)a[6] + (float)b[6] + (float)c[6] + (float)d[6];
  hi.w = (float)a[7] + (float)b[7] + (float)c[7] + (float)d[7];
  reinterpret_cast<float4*>(out)[i * 2] = lo;
  reinterpret_cast<float4*>(out)[i * 2 + 1] = hi;
}

// ---------------- row softmax: one wave per row ----------------
__global__ __launch_bounds__(256) void softmax_kernel(const ushort* __restrict__ S,
                                                      ushort* __restrict__ P) {
  const int wave = threadIdx.x >> 6, lane = threadIdx.x & 63;
  const int row = blockIdx.x * 4 + wave;
  const ushort* s = S + (size_t)row * SEQ;
  float v[64];
#pragma unroll
  for (int i = 0; i < 8; i++) {
    f16x8 h = reinterpret_cast<const f16x8*>(s)[i * 64 + lane];
#pragma unroll
    for (int j = 0; j < 8; j++) v[i * 8 + j] = (float)h[j];
  }
  float m = v[0];
#pragma unroll
  for (int j = 1; j < 64; j++) m = fmaxf(m, v[j]);
#pragma unroll
  for (int o = 32; o > 0; o >>= 1) m = fmaxf(m, __shfl_xor(m, o, 64));
  float sum = 0.f;
#pragma unroll
  for (int j = 0; j < 64; j++) {
    v[j] = __expf(v[j] - m);
    sum += v[j];
  }
#pragma unroll
  for (int o = 32; o > 0; o >>= 1) sum += __shfl_xor(sum, o, 64);
  float inv = 1.0f / sum;
  ushort* p = P + (size_t)row * SEQ;
#pragma unroll
  for (int i = 0; i < 8; i++) {
    f16x8 h;
#pragma unroll
    for (int j = 0; j < 8; j++) h[j] = (_Float16)(v[i * 8 + j] * inv);
    reinterpret_cast<f16x8*>(p)[i * 64 + lane] = h;
  }
}

extern "C" void kernel_launch(void* const* d_in, const int* in_sizes, int n_in,
                              void* d_out, int out_size, void* d_ws, size_t ws_size,
                              hipStream_t stream) {
  const float* X = (const float*)d_in[0];
  const float* Wk = (const float*)d_in[1];
  const float* Wv = (const float*)d_in[2];
  const float* Wq = (const float*)d_in[3];

  char* ws = (char*)d_ws;
  size_t off = 0;
  ushort* Xh = (ushort*)(ws + off); off += (size_t)SEQ * DIM * 2;      // 8 MB
  ushort* Wt = (ushort*)(ws + off); off += (size_t)3 * DIM * DIM * 2;  // 6 MB
  ushort* Kh = (ushort*)(ws + off); off += (size_t)SEQ * DIM * 2;      // 8 MB
  ushort* Qh = (ushort*)(ws + off); off += (size_t)SEQ * DIM * 2;      // 8 MB
  ushort* Vt = (ushort*)(ws + off); off += (size_t)SEQ * DIM * 2;      // 8 MB
  ushort* S = (ushort*)(ws + off);  off += (size_t)SEQ * SEQ * 2;      // 32 MB (reused as partials)
  ushort* P = (ushort*)(ws + off);  off += (size_t)SEQ * SEQ * 2;      // 32 MB

  ushort* Part = S;  // 4 x [SEQ,DIM] fp16 partials alias S; S dead after softmax

  convert_all_kernel<<<dim3(32, 32, 4), dim3(32, 8), 0, stream>>>(X, Wk, Wv, Wq, Xh, Wt);
  proj_kernel<<<dim3(256, 1, 3), 256, 0, stream>>>(Xh, Wt, Kh, Qh, Vt);
  score_kernel<<<512, 256, 0, stream>>>(Kh, Qh, S);
  softmax_kernel<<<1024, 256, 0, stream>>>(S, P);
  out_splitk_kernel<<<512, 256, 0, stream>>>(P, Vt, Part);
  reduce4_kernel<<<SEQ * DIM / 8 / 256, 256, 0, stream>>>(Part, (float*)d_out, SEQ * DIM / 8);
}